// Round 6
// baseline (376.354 us; speedup 1.0000x reference)
//
#include <hip/hip_runtime.h>
#include <math.h>

namespace {

constexpr int NN  = 50000;
constexpr int CC  = 128;
constexpr int EMn = 1000000;
constexpr int ESn = 200000;

using f32x4  = __attribute__((ext_vector_type(4))) float;
using short8 = __attribute__((ext_vector_type(8))) short;

__device__ __forceinline__ ushort f2bf(float f) {
  unsigned u = __float_as_uint(f);
  return (ushort)((u + 0x7fffu + ((u >> 16) & 1u)) >> 16);   // RNE
}
__device__ __forceinline__ float softplusf(float x) {
  return (x > 20.f) ? x : log1pf(expf(x));
}
__device__ __forceinline__ int sdot4i(unsigned a, unsigned b, int c) {
#if __has_builtin(__builtin_amdgcn_sdot4)
  return __builtin_amdgcn_sdot4((int)a, (int)b, c, false);
#else
  int r = c;
#pragma unroll
  for (int k = 0; k < 4; k++) {
    int xa = ((int)(a << (24 - 8 * k))) >> 24;
    int xb = ((int)(b << (24 - 8 * k))) >> 24;
    r += xa * xb;
  }
  return r;
#endif
}
__device__ __forceinline__ unsigned pack4(float a, float b, float c, float d) {
  int ia = __float2int_rn(a), ib = __float2int_rn(b);
  int ic = __float2int_rn(c), id = __float2int_rn(d);
  return (unsigned)(ia & 255) | ((unsigned)(ib & 255) << 8) |
         ((unsigned)(ic & 255) << 16) | ((unsigned)(id & 255) << 24);
}

// ---- K0: init scratch ----
__global__ void k_init(int* __restrict__ pidx, float* __restrict__ den,
                       float* __restrict__ num, float* __restrict__ cnt) {
  int i = blockIdx.x * blockDim.x + threadIdx.x;
  if (i < NN) { pidx[i] = -1; den[i] = 0.f; num[i] = 0.f; cnt[i] = 0.f; }
}

// ---- K_cvtq: per-row int8 quantization ----
__global__ void k_cvtq(const float* __restrict__ nodes, const float* __restrict__ nbrs,
                       char* __restrict__ qnodes, char* __restrict__ qunit,
                       char* __restrict__ qnbrs, float* __restrict__ nscale,
                       float* __restrict__ nbscale) {
  int row = blockIdx.x * 16 + (threadIdx.x >> 4);
  int li = threadIdx.x & 15;
  if (row >= 2 * NN) return;
  bool isn = row < NN;
  int r = isn ? row : row - NN;
  const float* src = (isn ? nodes : nbrs) + (size_t)r * CC;
  float4 x0 = *(const float4*)(src + li * 8);
  float4 x1 = *(const float4*)(src + li * 8 + 4);
  float v[8] = {x0.x, x0.y, x0.z, x0.w, x1.x, x1.y, x1.z, x1.w};
  float amax = 0.f, sq = 0.f;
#pragma unroll
  for (int j = 0; j < 8; j++) { amax = fmaxf(amax, fabsf(v[j])); sq += v[j] * v[j]; }
#pragma unroll
  for (int off = 1; off < 16; off <<= 1) {
    amax = fmaxf(amax, __shfl_xor(amax, off, 64));
    sq += __shfl_xor(sq, off, 64);
  }
  amax = fmaxf(amax, 1e-8f);
  float rs = 127.f / amax;
  uint2 p;
  p.x = pack4(v[0] * rs, v[1] * rs, v[2] * rs, v[3] * rs);
  p.y = pack4(v[4] * rs, v[5] * rs, v[6] * rs, v[7] * rs);
  if (isn) {
    *(uint2*)(qnodes + (size_t)r * CC + li * 8) = p;
    float ru = 127.f / fmaxf(sqrtf(sq), 1e-8f);
    uint2 pu;
    pu.x = pack4(v[0] * ru, v[1] * ru, v[2] * ru, v[3] * ru);
    pu.y = pack4(v[4] * ru, v[5] * ru, v[6] * ru, v[7] * ru);
    *(uint2*)(qunit + (size_t)r * CC + li * 8) = pu;
    if (li == 0) nscale[r] = amax / 127.f;
  } else {
    *(uint2*)(qnbrs + (size_t)r * CC + li * 8) = p;
    if (li == 0) nbscale[r] = amax / 127.f;
  }
}

// ---- K2: partner_index scatter-max ----
__global__ void k_partner(const int* __restrict__ ss, const int* __restrict__ sd,
                          int* __restrict__ pidx) {
  int i = blockIdx.x * blockDim.x + threadIdx.x;
  if (i >= 2 * ESn) return;
  int partner = (i < ESn) ? sd[i] : ss[i - ESn];
  atomicMax(&pidx[partner], i);
}

// ---- K3: cos + segmented sums, ONE LANE PER EDGE (max loads in flight) ----
__global__ void k_cos1(const char* __restrict__ qunit,
                       const int* __restrict__ ss, const int* __restrict__ sd,
                       const int* __restrict__ ms, const int* __restrict__ md,
                       const int* __restrict__ pidx, float* __restrict__ den,
                       float* __restrict__ num, float* __restrict__ cnt) {
  int e = blockIdx.x * blockDim.x + threadIdx.x;
  if (e >= EMn) return;
  int d = md[e];
  int pi = pidx[d];
  if (pi < 0) return;
  int q = (pi < ESn) ? ss[pi] : sd[pi - ESn];
  int s = ms[e];
  const uint4* rq = (const uint4*)(qunit + (size_t)q * CC);
  const uint4* rs = (const uint4*)(qunit + (size_t)s * CC);
  uint4 a0 = rq[0], a1 = rq[1], a2 = rq[2], a3 = rq[3];
  uint4 a4 = rq[4], a5 = rq[5], a6 = rq[6], a7 = rq[7];
  uint4 b0 = rs[0], b1 = rs[1], b2 = rs[2], b3 = rs[3];
  uint4 b4 = rs[4], b5 = rs[5], b6 = rs[6], b7 = rs[7];
  int acc = 0;
  acc = sdot4i(a0.x, b0.x, acc); acc = sdot4i(a0.y, b0.y, acc);
  acc = sdot4i(a0.z, b0.z, acc); acc = sdot4i(a0.w, b0.w, acc);
  acc = sdot4i(a1.x, b1.x, acc); acc = sdot4i(a1.y, b1.y, acc);
  acc = sdot4i(a1.z, b1.z, acc); acc = sdot4i(a1.w, b1.w, acc);
  acc = sdot4i(a2.x, b2.x, acc); acc = sdot4i(a2.y, b2.y, acc);
  acc = sdot4i(a2.z, b2.z, acc); acc = sdot4i(a2.w, b2.w, acc);
  acc = sdot4i(a3.x, b3.x, acc); acc = sdot4i(a3.y, b3.y, acc);
  acc = sdot4i(a3.z, b3.z, acc); acc = sdot4i(a3.w, b3.w, acc);
  acc = sdot4i(a4.x, b4.x, acc); acc = sdot4i(a4.y, b4.y, acc);
  acc = sdot4i(a4.z, b4.z, acc); acc = sdot4i(a4.w, b4.w, acc);
  acc = sdot4i(a5.x, b5.x, acc); acc = sdot4i(a5.y, b5.y, acc);
  acc = sdot4i(a5.z, b5.z, acc); acc = sdot4i(a5.w, b5.w, acc);
  acc = sdot4i(a6.x, b6.x, acc); acc = sdot4i(a6.y, b6.y, acc);
  acc = sdot4i(a6.z, b6.z, acc); acc = sdot4i(a6.w, b6.w, acc);
  acc = sdot4i(a7.x, b7.x, acc); acc = sdot4i(a7.y, b7.y, acc);
  acc = sdot4i(a7.z, b7.z, acc); acc = sdot4i(a7.w, b7.w, acc);
  float cv = (float)acc * (1.0f / (127.f * 127.f));
  float wv = expf(10.0f * cv);              // softmax shift-invariant: no max pass
  atomicAdd(&den[q], wv);
  atomicAdd(&num[q], wv * cv);
  atomicAdd(&cnt[q], 1.0f);
}

// ---- K5: cong_node ----
__global__ void k_cong(const float* __restrict__ den, const float* __restrict__ num,
                       const float* __restrict__ cnt, float* __restrict__ cong) {
  int n = blockIdx.x * blockDim.x + threadIdx.x;
  if (n >= NN) return;
  float c = cnt[n];
  cong[n] = (c > 0.f) ? (num[n] / den[n]) / c : 0.f;
}

// ---- K_prep: transpose + bf16-convert W0 [256x256] and W1 [256x128] ----
__global__ void k_prep(const float* __restrict__ W0, const float* __restrict__ W1,
                       ushort* __restrict__ w0t, ushort* __restrict__ w1t) {
  __shared__ float tl[32][33];
  int b = blockIdx.x;
  const float* src; ushort* dst; int N, tk, tn;
  if (b < 64) { src = W0; dst = w0t; N = 256; tk = b >> 3; tn = b & 7; }
  else        { b -= 64; src = W1; dst = w1t; N = 128; tk = b >> 2; tn = b & 3; }
  int tx = threadIdx.x & 31, ty = threadIdx.x >> 5;
#pragma unroll
  for (int yy = 0; yy < 32; yy += 8)
    tl[ty + yy][tx] = src[(size_t)(tk * 32 + ty + yy) * N + tn * 32 + tx];
  __syncthreads();
#pragma unroll
  for (int yy = 0; yy < 32; yy += 8)
    dst[(size_t)(tn * 32 + ty + yy) * 256 + tk * 32 + tx] = f2bf(tl[tx][ty + yy]);
}

// ---- K6: fused MFMA MLP + heads. 32 edges/block, 4 waves col-split, 5 barriers ----
__global__ __launch_bounds__(256) void k_mlp(
    const char* __restrict__ qnodes, const float* __restrict__ nscale,
    const char* __restrict__ qnbrs, const float* __restrict__ nbscale,
    const int* __restrict__ ssrc, const int* __restrict__ sdst,
    const float* __restrict__ cong,
    const ushort* __restrict__ w0t, const ushort* __restrict__ w1t,
    const float* __restrict__ b0, const float* __restrict__ g0, const float* __restrict__ be0,
    const float* __restrict__ b1, const float* __restrict__ g1, const float* __restrict__ be1,
    const float* __restrict__ Wp, const float* __restrict__ bp,
    const float* __restrict__ Ww, const float* __restrict__ bw,
    const float* __restrict__ sscale, const float* __restrict__ sshift,
    const float* __restrict__ craw, float* __restrict__ out) {
  __shared__ ushort tile[32][256];          // combined (bf16, XOR-swizzled), reused for h_ln
  __shared__ float pstatA[32][8];           // LN1 partials [(s,sq) x 4 waves]
  __shared__ float pstatB[32][8];           // LN2 partials
  __shared__ float pstatC[32][8];           // head partials [(pd,ws) x 4 waves]
  __shared__ float nsimb[32];
  __shared__ int   eidx[32][2];

  const int t = threadIdx.x;
  const int w = t >> 6, l = t & 63;
  const int li = l & 15, hi = l >> 4;
  const int s0 = blockIdx.x * 32;
  const int r8 = t >> 3, q8 = t & 7;        // staging/nbr row + col-eighth

  if (t < 32) { eidx[t][0] = ssrc[s0 + t]; eidx[t][1] = sdst[s0 + t]; }

  // ---- issue ALL gathers up front ----
  int es = ssrc[s0 + r8], ed = sdst[s0 + r8];
  uint4 xu = ((const uint4*)(qnodes + (size_t)es * CC))[q8];
  uint4 yu = ((const uint4*)(qnodes + (size_t)ed * CC))[q8];
  uint4 xn = ((const uint4*)(qnbrs + (size_t)es * CC))[q8];
  uint4 yn = ((const uint4*)(qnbrs + (size_t)ed * CC))[q8];
  float sxs = nscale[es], sxd = nscale[ed];
  float nbs = nbscale[es] * nbscale[ed];

  // ---- stage combined = [a | m] bf16 (16 elems per thread), swizzled ----
  {
    unsigned xd[4] = {xu.x, xu.y, xu.z, xu.w};
    unsigned yd[4] = {yu.x, yu.y, yu.z, yu.w};
    int sw = (r8 & 7) << 3;
#pragma unroll
    for (int c = 0; c < 2; c++) {
      short8 a8, m8;
#pragma unroll
      for (int dk = 0; dk < 8; dk++) {
        int dd = c * 2 + (dk >> 2), k = dk & 3;
        float fx = (float)(((int)(xd[dd] << (24 - 8 * k))) >> 24) * sxs;
        float fy = (float)(((int)(yd[dd] << (24 - 8 * k))) >> 24) * sxd;
        a8[dk] = (short)f2bf(fx + fy);
        m8[dk] = (short)f2bf(fx * fy);
      }
      int base = q8 * 16 + c * 8;
      *(short8*)&tile[r8][base ^ sw] = a8;
      *(short8*)&tile[r8][(128 + base) ^ sw] = m8;
    }
  }
  // ---- nbrs similarity (int8 dot over the 8 lanes owning this edge) ----
  {
    int acc8 = 0;
    acc8 = sdot4i(xn.x, yn.x, acc8); acc8 = sdot4i(xn.y, yn.y, acc8);
    acc8 = sdot4i(xn.z, yn.z, acc8); acc8 = sdot4i(xn.w, yn.w, acc8);
    acc8 += __shfl_xor(acc8, 1, 64);
    acc8 += __shfl_xor(acc8, 2, 64);
    acc8 += __shfl_xor(acc8, 4, 64);
    if (q8 == 0) nsimb[r8] = (float)acc8 * nbs;
  }
  __syncthreads();                          // B1: tile ready

  const int swl = (li & 7) << 3;
  const int n0 = w * 64;                    // GEMM1 col base

  // ---- GEMM1: h cols [n0, n0+64) for all 32 edges ----
  f32x4 acc[4][2];
#pragma unroll
  for (int nf = 0; nf < 4; nf++) {
    float bv = b0[n0 + nf * 16 + li];
    acc[nf][0] = {bv, bv, bv, bv};
    acc[nf][1] = {bv, bv, bv, bv};
  }
#pragma unroll
  for (int kk = 0; kk < 8; kk++) {
    short8 a[2], b[4];
    a[0] = *(const short8*)&tile[li][(kk * 32 + hi * 8) ^ swl];
    a[1] = *(const short8*)&tile[16 + li][(kk * 32 + hi * 8) ^ swl];
#pragma unroll
    for (int nf = 0; nf < 4; nf++)
      b[nf] = *(const short8*)(w0t + (size_t)(n0 + nf * 16 + li) * 256 + kk * 32 + hi * 8);
#pragma unroll
    for (int nf = 0; nf < 4; nf++)
#pragma unroll
      for (int ef = 0; ef < 2; ef++)
        acc[nf][ef] = __builtin_amdgcn_mfma_f32_16x16x32_bf16(a[ef], b[nf], acc[nf][ef], 0, 0, 0);
  }

  // ---- LN1 partials -> pstatA ----
  {
    f32x4 ps[2], qs[2];
#pragma unroll
    for (int ef = 0; ef < 2; ef++) {
      ps[ef] = acc[0][ef] + acc[1][ef] + acc[2][ef] + acc[3][ef];
      qs[ef] = acc[0][ef] * acc[0][ef] + acc[1][ef] * acc[1][ef]
             + acc[2][ef] * acc[2][ef] + acc[3][ef] * acc[3][ef];
    }
#pragma unroll
    for (int ef = 0; ef < 2; ef++)
#pragma unroll
      for (int j = 0; j < 4; j++)
#pragma unroll
        for (int off = 1; off < 16; off <<= 1) {
          ps[ef][j] += __shfl_xor(ps[ef][j], off, 64);
          qs[ef][j] += __shfl_xor(qs[ef][j], off, 64);
        }
    if (li < 4) {
#pragma unroll
      for (int ef = 0; ef < 2; ef++) {
        int r = ef * 16 + hi * 4 + li;
        pstatA[r][2 * w] = ps[ef][li];
        pstatA[r][2 * w + 1] = qs[ef][li];
      }
    }
  }
  __syncthreads();                          // B2: pstatA ready

  // ---- LN1 normalize + relu -> tile (per-thread mu/rstd from pstatA) ----
  {
    float mu1[2][4], rs1[2][4];
#pragma unroll
    for (int ef = 0; ef < 2; ef++)
#pragma unroll
      for (int j = 0; j < 4; j++) {
        int r = ef * 16 + hi * 4 + j;
        float4 pa = *(const float4*)&pstatA[r][0];
        float4 pb = *(const float4*)&pstatA[r][4];
        float s = pa.x + pa.z + pb.x + pb.z;
        float sq = pa.y + pa.w + pb.y + pb.w;
        float mu = s * (1.f / 256.f);
        mu1[ef][j] = mu;
        rs1[ef][j] = rsqrtf(sq * (1.f / 256.f) - mu * mu + 1e-5f);
      }
#pragma unroll
    for (int nf = 0; nf < 4; nf++) {
      int col = n0 + nf * 16 + li;
      float gv = g0[col], bev = be0[col];
#pragma unroll
      for (int ef = 0; ef < 2; ef++)
#pragma unroll
        for (int j = 0; j < 4; j++) {
          int r = ef * 16 + hi * 4 + j;
          float v = fmaxf((acc[nf][ef][j] - mu1[ef][j]) * rs1[ef][j] * gv + bev, 0.f);
          tile[r][col ^ ((r & 7) << 3)] = f2bf(v);
        }
    }
  }
  __syncthreads();                          // B3: h_ln ready

  // ---- GEMM2: ef cols [16w, 16w+16)x2 for all 32 edges ----
  const int n2 = w * 32;
  f32x4 acc2[2][2];
#pragma unroll
  for (int nf = 0; nf < 2; nf++) {
    float bv = b1[n2 + nf * 16 + li];
    acc2[nf][0] = {bv, bv, bv, bv};
    acc2[nf][1] = {bv, bv, bv, bv};
  }
#pragma unroll
  for (int kk = 0; kk < 8; kk++) {
    short8 a[2], b[2];
    a[0] = *(const short8*)&tile[li][(kk * 32 + hi * 8) ^ swl];
    a[1] = *(const short8*)&tile[16 + li][(kk * 32 + hi * 8) ^ swl];
#pragma unroll
    for (int nf = 0; nf < 2; nf++)
      b[nf] = *(const short8*)(w1t + (size_t)(n2 + nf * 16 + li) * 256 + kk * 32 + hi * 8);
#pragma unroll
    for (int nf = 0; nf < 2; nf++)
#pragma unroll
      for (int ef = 0; ef < 2; ef++)
        acc2[nf][ef] = __builtin_amdgcn_mfma_f32_16x16x32_bf16(a[ef], b[nf], acc2[nf][ef], 0, 0, 0);
  }

  // ---- LN2 partials -> pstatB ----
  {
    f32x4 ps[2], qs[2];
#pragma unroll
    for (int ef = 0; ef < 2; ef++) {
      ps[ef] = acc2[0][ef] + acc2[1][ef];
      qs[ef] = acc2[0][ef] * acc2[0][ef] + acc2[1][ef] * acc2[1][ef];
    }
#pragma unroll
    for (int ef = 0; ef < 2; ef++)
#pragma unroll
      for (int j = 0; j < 4; j++)
#pragma unroll
        for (int off = 1; off < 16; off <<= 1) {
          ps[ef][j] += __shfl_xor(ps[ef][j], off, 64);
          qs[ef][j] += __shfl_xor(qs[ef][j], off, 64);
        }
    if (li < 4) {
#pragma unroll
      for (int ef = 0; ef < 2; ef++) {
        int r = ef * 16 + hi * 4 + li;
        pstatB[r][2 * w] = ps[ef][li];
        pstatB[r][2 * w + 1] = qs[ef][li];
      }
    }
  }
  __syncthreads();                          // B4: pstatB ready

  // ---- LN2 normalize + relu + head partial dots -> pstatC ----
  {
    float pdp[2][4] = {{0,0,0,0},{0,0,0,0}};
    float wsp[2][4] = {{0,0,0,0},{0,0,0,0}};
    float mu2[2][4], rs2[2][4];
#pragma unroll
    for (int ef = 0; ef < 2; ef++)
#pragma unroll
      for (int j = 0; j < 4; j++) {
        int r = ef * 16 + hi * 4 + j;
        float4 pa = *(const float4*)&pstatB[r][0];
        float4 pb = *(const float4*)&pstatB[r][4];
        float s = pa.x + pa.z + pb.x + pb.z;
        float sq = pa.y + pa.w + pb.y + pb.w;
        float mu = s * (1.f / 128.f);
        mu2[ef][j] = mu;
        rs2[ef][j] = rsqrtf(sq * (1.f / 128.f) - mu * mu + 1e-5f);
      }
#pragma unroll
    for (int nf = 0; nf < 2; nf++) {
      int col = n2 + nf * 16 + li;
      float gv = g1[col], bev = be1[col];
      float wpv = Wp[col], wwv = Ww[col];
#pragma unroll
      for (int ef = 0; ef < 2; ef++)
#pragma unroll
        for (int j = 0; j < 4; j++) {
          float e = fmaxf((acc2[nf][ef][j] - mu2[ef][j]) * rs2[ef][j] * gv + bev, 0.f);
          pdp[ef][j] += e * wpv;
          wsp[ef][j] += e * wwv;
        }
    }
#pragma unroll
    for (int ef = 0; ef < 2; ef++)
#pragma unroll
      for (int j = 0; j < 4; j++)
#pragma unroll
        for (int off = 1; off < 16; off <<= 1) {
          pdp[ef][j] += __shfl_xor(pdp[ef][j], off, 64);
          wsp[ef][j] += __shfl_xor(wsp[ef][j], off, 64);
        }
    if (li < 4) {
#pragma unroll
      for (int ef = 0; ef < 2; ef++) {
        int r = ef * 16 + hi * 4 + li;
        pstatC[r][2 * w] = pdp[ef][li];
        pstatC[r][2 * w + 1] = wsp[ef][li];
      }
    }
  }
  __syncthreads();                          // B5: pstatC ready

  if (t < 32) {
    float4 pa = *(const float4*)&pstatC[t][0];
    float4 pb = *(const float4*)&pstatC[t][4];
    float pd = pa.x + pa.z + pb.x + pb.z;
    float ws = pa.y + pa.w + pb.y + pb.w;
    float nsim = nsimb[t];
    int esf = eidx[t][0], edf = eidx[t][1];
    float u0 = softplusf(craw[0]), u1 = softplusf(craw[1]), u2 = softplusf(craw[2]);
    float usum = u0 + u1 + u2;
    float c0 = u0 / usum, c1 = u1 / usum, c2 = u2 / usum;
    float sc = sscale[0], sh = sshift[0];
    int sidx = s0 + t;
    out[3 * sidx + 0] = c0 * (pd + bp[0]);
    out[3 * sidx + 1] = c1 * (sc * (nsim + sh));
    out[3 * sidx + 2] = c2 * (sc * (cong[esf] + cong[edf] + sh));
    out[3 * ESn + sidx] = fmaxf(ws + nsim * Ww[128] + bw[0], 0.f);
    if (blockIdx.x == 0 && t == 0) {
      out[4 * ESn + 0] = c0; out[4 * ESn + 1] = c1; out[4 * ESn + 2] = c2;
    }
  }
}

} // namespace

extern "C" void kernel_launch(void* const* d_in, const int* in_sizes, int n_in,
                              void* d_out, int out_size, void* d_ws, size_t ws_size,
                              hipStream_t stream) {
  (void)in_sizes; (void)n_in; (void)out_size; (void)ws_size;
  const float* nodes  = (const float*)d_in[0];
  const float* nbrs   = (const float*)d_in[1];
  const int* sup_src  = (const int*)d_in[2];
  const int* sup_dst  = (const int*)d_in[3];
  const int* msg_src  = (const int*)d_in[4];
  const int* msg_dst  = (const int*)d_in[5];
  // d_in[6] message_edgestr: dead
  const float* W0  = (const float*)d_in[7];
  const float* b0  = (const float*)d_in[8];
  const float* g0  = (const float*)d_in[9];
  const float* be0 = (const float*)d_in[10];
  const float* W1  = (const float*)d_in[11];
  const float* b1  = (const float*)d_in[12];
  const float* g1  = (const float*)d_in[13];
  const float* be1 = (const float*)d_in[14];
  const float* Wp  = (const float*)d_in[15];
  const float* bp  = (const float*)d_in[16];
  const float* Ww  = (const float*)d_in[17];
  const float* bw  = (const float*)d_in[18];
  const float* sscale = (const float*)d_in[19];
  const float* sshift = (const float*)d_in[20];
  const float* craw   = (const float*)d_in[21];
  // d_in[22..27] mm_*: dead
  float* out = (float*)d_out;

  char* p = (char*)d_ws;
  auto take = [&](size_t bytes) -> char* {
    char* r = p; p += (bytes + 255) & ~(size_t)255; return r;
  };
  ushort* w0t     = (ushort*)take((size_t)256 * 256 * 2);
  ushort* w1t     = (ushort*)take((size_t)128 * 256 * 2);
  char*   qnodes  = take((size_t)NN * CC);
  char*   qunit   = take((size_t)NN * CC);
  char*   qnbrs   = take((size_t)NN * CC);
  float*  nscale  = (float*)take((size_t)NN * 4);
  float*  nbscale = (float*)take((size_t)NN * 4);
  int*    pidx    = (int*)take((size_t)NN * 4);
  float*  den     = (float*)take((size_t)NN * 4);
  float*  num     = (float*)take((size_t)NN * 4);
  float*  cnt     = (float*)take((size_t)NN * 4);
  float*  cong    = (float*)take((size_t)NN * 4);

  k_init<<<(NN + 255) / 256, 256, 0, stream>>>(pidx, den, num, cnt);
  k_cvtq<<<(2 * NN + 15) / 16, 256, 0, stream>>>(nodes, nbrs, qnodes, qunit, qnbrs,
                                                 nscale, nbscale);
  k_prep<<<96, 256, 0, stream>>>(W0, W1, w0t, w1t);
  k_partner<<<(2 * ESn + 255) / 256, 256, 0, stream>>>(sup_src, sup_dst, pidx);
  k_cos1<<<(EMn + 255) / 256, 256, 0, stream>>>(qunit, sup_src, sup_dst, msg_src, msg_dst,
                                                pidx, den, num, cnt);
  k_cong<<<(NN + 255) / 256, 256, 0, stream>>>(den, num, cnt, cong);
  k_mlp<<<ESn / 32, 256, 0, stream>>>(qnodes, nscale, qnbrs, nbscale,
                                      sup_src, sup_dst, cong,
                                      w0t, w1t, b0, g0, be0, b1, g1, be1,
                                      Wp, bp, Ww, bw, sscale, sshift, craw, out);
}